// Round 1
// 449.043 us; speedup vs baseline: 12.5265x; 12.5265x over previous
//
#include <hip/hip_runtime.h>

typedef unsigned short u16;
typedef unsigned int u32;
using short8 = __attribute__((__ext_vector_type__(8))) short;
using f32x4  = __attribute__((__ext_vector_type__(4))) float;

#define DIM 768
#define QKV3 2304
#define SEQ 1024
#define SCALE 0.14433756729740643f  // 48^-0.5

__device__ __forceinline__ u16 f2bf(float f) {
  u32 u = __float_as_uint(f);
  return (u16)((u + 0x7fffu + ((u >> 16) & 1u)) >> 16);  // RNE
}
__device__ __forceinline__ u32 packbf(float lo, float hi) {
  return (u32)f2bf(lo) | ((u32)f2bf(hi) << 16);
}
__device__ __forceinline__ void store1(u16* p, float v) { *p = f2bf(v); }
__device__ __forceinline__ void store1(float* p, float v) { *p = v; }

__device__ __forceinline__ f32x4 mfma16(short8 a, short8 b, f32x4 c) {
  return __builtin_amdgcn_mfma_f32_16x16x32_bf16(a, b, c, 0, 0, 0);
}

// stage 8 contiguous elements into LDS as bf16
__device__ __forceinline__ void stage8(u16* dst, const float* src) {
  float4 a = *(const float4*)src;
  float4 b = *(const float4*)(src + 4);
  short8 v;
  v[0] = (short)f2bf(a.x); v[1] = (short)f2bf(a.y);
  v[2] = (short)f2bf(a.z); v[3] = (short)f2bf(a.w);
  v[4] = (short)f2bf(b.x); v[5] = (short)f2bf(b.y);
  v[6] = (short)f2bf(b.z); v[7] = (short)f2bf(b.w);
  *(short8*)dst = v;
}
__device__ __forceinline__ void stage8(u16* dst, const u16* src) {
  *(short8*)dst = *(const short8*)src;
}

// ---------------- MFMA GEMM: C[M][N] = A[M][K] @ W[N][K]^T + bias[N]
// 128x128 tile, BK=32, 256 threads (4 waves), wave -> 64x64 via 4x4 16x16 frags.
template <typename TA, typename TO>
__global__ __launch_bounds__(256, 2)
void gemm_mfma(const TA* __restrict__ A, const float* __restrict__ W,
               const float* __restrict__ bias, TO* __restrict__ C,
               int M, int N, int K) {
  __shared__ __align__(16) u16 As[128 * 40];  // [row][k pad 40] bf16
  __shared__ __align__(16) u16 Bs[128 * 40];
  const int tid = threadIdx.x;
  const int lane = tid & 63;
  const int wv = tid >> 6;
  const int lq = lane & 15;   // frag row/col
  const int lc = lane >> 4;   // frag k-chunk / out row group
  const int wm = wv >> 1, wn = wv & 1;
  const int row0 = blockIdx.y * 128, col0 = blockIdx.x * 128;

  f32x4 acc[4][4];
#pragma unroll
  for (int i = 0; i < 4; ++i)
#pragma unroll
    for (int j = 0; j < 4; ++j) acc[i][j] = (f32x4){0.f, 0.f, 0.f, 0.f};

  for (int k0 = 0; k0 < K; k0 += 32) {
    __syncthreads();
#pragma unroll
    for (int t = 0; t < 2; ++t) {
      int id = tid + t * 256;
      int r = id >> 2, kc = (id & 3) * 8;
      stage8(As + r * 40 + kc, A + (size_t)(row0 + r) * K + k0 + kc);
      stage8(Bs + r * 40 + kc, W + (size_t)(col0 + r) * K + k0 + kc);
    }
    __syncthreads();
    short8 af[4], bf8[4];
#pragma unroll
    for (int i = 0; i < 4; ++i)
      af[i] = *(const short8*)(As + (wm * 64 + i * 16 + lq) * 40 + lc * 8);
#pragma unroll
    for (int j = 0; j < 4; ++j)
      bf8[j] = *(const short8*)(Bs + (wn * 64 + j * 16 + lq) * 40 + lc * 8);
#pragma unroll
    for (int i = 0; i < 4; ++i)
#pragma unroll
      for (int j = 0; j < 4; ++j) acc[i][j] = mfma16(af[i], bf8[j], acc[i][j]);
  }
#pragma unroll
  for (int j = 0; j < 4; ++j) {
    int col = col0 + wn * 64 + j * 16 + lq;
    float bv = bias[col];
#pragma unroll
    for (int i = 0; i < 4; ++i)
#pragma unroll
      for (int r = 0; r < 4; ++r) {
        int row = row0 + wm * 64 + i * 16 + lc * 4 + r;
        store1(C + (size_t)row * N + col, acc[i][j][r] + bv);
      }
  }
}

// ---------------- Fused talking-heads attention, all-MFMA ----------------
// Block = (batch b, 32-query tile), 512 threads = 8 waves, KT=32 keys/tile.
// Pass 0: S=Q.K^T (MFMA) -> Sb bf16 -> L=wl'*S+bl (MFMA) -> Z += exp(L)
//   (no max subtraction: logits are O(1) for this problem; softmax is
//    shift-invariant so this is exact in fp32)
// Pass 1: recompute L, P=exp(L)*invZ -> Pb (in-place over Sb) ->
//   W2=ww*P+bw (MFMA) -> overlay W2 into Sb q-slice -> O += W2 @ V (MFMA)
// LDS: Ks[32][776] (K rows, d-contig), Sb[32 q][32 k][24 h-slot] (+q pad),
//      Vs[768 d][40 k-pad] (V transposed).  157 KB total.
#define KS_ELEMS 24848
#define ATTN_SMEM 160832

__global__ __launch_bounds__(512, 2)
void attn_kernel(const u16* __restrict__ qkv,
                 const float* __restrict__ wl, const float* __restrict__ bl,
                 const float* __restrict__ ww, const float* __restrict__ bw,
                 u16* __restrict__ obuf) {
  extern __shared__ __align__(16) u16 smem[];
  u16* const Ks = smem;                 // 24848 elems
  u16* const Sb = smem + KS_ELEMS;      // 24848 elems
  u16* const Vs = smem + 2 * KS_ELEMS;  // 30720 elems

  const int tid = threadIdx.x;
  const int wv = tid >> 6;
  const int lane = tid & 63;
  const int lq = lane & 15;
  const int lc = lane >> 4;
  const int b = blockIdx.x >> 5;
  const int qt = blockIdx.x & 31;
  const size_t tokQ = (size_t)b * SEQ + (size_t)qt * 32;
  const size_t tokB = (size_t)b * SEQ;
  const int h0 = wv * 2;  // wave's head pair (QK) / g2 pair (PV)

  // zero Ks+Sb once: spill/pad regions are read (as don't-care) by frags and
  // must be finite (0 * NaN = NaN would poison the MFMA otherwise).
  {
    u32* z = (u32*)smem;
    for (int i = tid; i < 2 * KS_ELEMS / 2; i += 512) z[i] = 0u;
  }

  // Q fragments in registers: A[row=q(lq)][kd=d(lc*8+e)], d 48..63 zero
  short8 qf[2][2][2];  // [hh][qsub][dchunk]
#pragma unroll
  for (int hh = 0; hh < 2; ++hh)
#pragma unroll
    for (int qs = 0; qs < 2; ++qs) {
      const u16* qp = qkv + (tokQ + qs * 16 + lq) * QKV3 + (h0 + hh) * 48;
      qf[hh][qs][0] = *(const short8*)(qp + lc * 8);
      short8 z8 = {0, 0, 0, 0, 0, 0, 0, 0};
      if (lc < 2) z8 = *(const short8*)(qp + 32 + lc * 8);
      qf[hh][qs][1] = z8;
    }

  // mix A-frags: wl' = wl*SCALE (scale folded), zero-padded h 16..31
  short8 wlF = {0, 0, 0, 0, 0, 0, 0, 0};
  short8 wwF = {0, 0, 0, 0, 0, 0, 0, 0};
  if (lc < 2) {
#pragma unroll
    for (int e = 0; e < 8; ++e) {
      wlF[e] = (short)f2bf(wl[lq * 16 + lc * 8 + e] * SCALE);
      wwF[e] = (short)f2bf(ww[lq * 16 + lc * 8 + e]);
    }
  }
  float blr[4], bwr[4];
#pragma unroll
  for (int r = 0; r < 4; ++r) { blr[r] = bl[lc * 4 + r]; bwr[r] = bw[lc * 4 + r]; }

  float Zac[4][4];  // [q-own i][r]; partial over this lane's k columns
  float invZ[4][4];
#pragma unroll
  for (int i = 0; i < 4; ++i)
#pragma unroll
    for (int r = 0; r < 4; ++r) Zac[i][r] = 0.f;

  f32x4 O[2][3][2];  // [hh][dtile][qsub]
#pragma unroll
  for (int hh = 0; hh < 2; ++hh)
#pragma unroll
    for (int dt = 0; dt < 3; ++dt)
#pragma unroll
      for (int qs = 0; qs < 2; ++qs) O[hh][dt][qs] = (f32x4){0.f, 0.f, 0.f, 0.f};

  for (int pass = 0; pass < 2; ++pass) {
    for (int kt = 0; kt < 32; ++kt) {
      __syncthreads();  // protect Ks/Sb/Vs vs prev-iter readers
      // stage K tile: [32 k][768 d] -> Ks[k][776]
#pragma unroll
      for (int t = 0; t < 6; ++t) {
        int j = t * 512 + tid;
        int kr = j / 96, cc = j - kr * 96;
        *(short8*)(Ks + kr * 776 + cc * 8) =
            *(const short8*)(qkv + (tokB + (size_t)kt * 32 + kr) * QKV3 + DIM + cc * 8);
      }
      if (pass) {
        // stage V transposed: Vs[d][k], k-pairs packed as u32
#pragma unroll
        for (int t = 0; t < 3; ++t) {
          int cc = (tid >> 4) + t * 32;  // d-chunk 0..95
          int kk = tid & 15;             // k-pair
          const u16* v0 = qkv + (tokB + (size_t)kt * 32 + 2 * kk) * QKV3 + 2 * DIM + cc * 8;
          short8 va = *(const short8*)v0;
          short8 vb = *(const short8*)(v0 + QKV3);
#pragma unroll
          for (int e = 0; e < 8; ++e)
            *(u32*)(Vs + (cc * 8 + e) * 40 + 2 * kk) =
                (u32)(u16)va[e] | ((u32)(u16)vb[e] << 16);
        }
      }
      __syncthreads();

      // ---- QK^T: wave's head pair, S[h][q][k] -> Sb[q][k*24 + h] bf16
#pragma unroll
      for (int ks = 0; ks < 2; ++ks) {
        short8 kf[2][2];
#pragma unroll
        for (int hh = 0; hh < 2; ++hh) {
          const u16* kb = Ks + (ks * 16 + lq) * 776 + (h0 + hh) * 48;
          kf[hh][0] = *(const short8*)(kb + lc * 8);
          kf[hh][1] = *(const short8*)(kb + 32 + lc * 8);  // d48..63 dont-care (A=0)
        }
#pragma unroll
        for (int qs = 0; qs < 2; ++qs) {
          f32x4 s0 = {0.f, 0.f, 0.f, 0.f}, s1 = {0.f, 0.f, 0.f, 0.f};
          s0 = mfma16(qf[0][qs][0], kf[0][0], s0);
          s0 = mfma16(qf[0][qs][1], kf[0][1], s0);
          s1 = mfma16(qf[1][qs][0], kf[1][0], s1);
          s1 = mfma16(qf[1][qs][1], kf[1][1], s1);
#pragma unroll
          for (int r = 0; r < 4; ++r) {
            int q = qs * 16 + lc * 4 + r;
            int k = ks * 16 + lq;
            *(u32*)(Sb + q * 776 + k * 24 + h0) = packbf(s0[r], s1[r]);
          }
        }
      }
      __syncthreads();

      // ---- mix phase: wave owns q = wv*4 + i
#pragma unroll
      for (int i = 0; i < 4; ++i) {
        const int q = wv * 4 + i;
        u16* const sq = Sb + q * 776;
        f32x4 L[2];
#pragma unroll
        for (int ks = 0; ks < 2; ++ks) {
          short8 sf = *(const short8*)(sq + (ks * 16 + lq) * 24 + lc * 8);
          f32x4 cin = {blr[0], blr[1], blr[2], blr[3]};
          L[ks] = mfma16(wlF, sf, cin);  // L[g=lc*4+r][k=ks*16+lq]
        }
        if (pass == 0) {
#pragma unroll
          for (int ks = 0; ks < 2; ++ks)
#pragma unroll
            for (int r = 0; r < 4; ++r) Zac[i][r] += __expf(L[ks][r]);
        } else {
          // P = exp(L)*invZ, in-place over Sb slots 0..15
#pragma unroll
          for (int ks = 0; ks < 2; ++ks) {
            float p0 = __expf(L[ks][0]) * invZ[i][0];
            float p1 = __expf(L[ks][1]) * invZ[i][1];
            float p2 = __expf(L[ks][2]) * invZ[i][2];
            float p3 = __expf(L[ks][3]) * invZ[i][3];
            u16* pp = sq + (ks * 16 + lq) * 24 + lc * 4;
            *(u32*)pp = packbf(p0, p1);
            *(u32*)(pp + 2) = packbf(p2, p3);
          }
          f32x4 W2[2];
#pragma unroll
          for (int ks = 0; ks < 2; ++ks) {
            short8 pf = *(const short8*)(sq + (ks * 16 + lq) * 24 + lc * 8);
            f32x4 cin = {bwr[0], bwr[1], bwr[2], bwr[3]};
            W2[ks] = mfma16(wwF, pf, cin);  // W2[g2=lc*4+r][k]
          }
          // overlay W2 into own q-slice: layout [g2*40 + k]
#pragma unroll
          for (int ks = 0; ks < 2; ++ks)
#pragma unroll
            for (int r = 0; r < 4; ++r)
              sq[(lc * 4 + r) * 40 + ks * 16 + lq] = f2bf(W2[ks][r]);
        }
      }

      if (pass) {
        __syncthreads();  // W2 visible to all waves
        // ---- PV: wave's g2 pair; O[q][d] += W2[g2][q][k] * V[k][g2*48+d]
#pragma unroll
        for (int hh = 0; hh < 2; ++hh) {
          const int g2 = h0 + hh;
          short8 w2f[2];
#pragma unroll
          for (int qs = 0; qs < 2; ++qs)
            w2f[qs] = *(const short8*)(Sb + (qs * 16 + lq) * 776 + g2 * 40 + lc * 8);
#pragma unroll
          for (int dt = 0; dt < 3; ++dt) {
            short8 vf = *(const short8*)(Vs + (g2 * 48 + dt * 16 + lq) * 40 + lc * 8);
#pragma unroll
            for (int qs = 0; qs < 2; ++qs)
              O[hh][dt][qs] = mfma16(w2f[qs], vf, O[hh][dt][qs]);
          }
        }
      }
    }
    if (pass == 0) {
      // reduce Z over the 16 k-lanes; all lanes end up with the full sum
#pragma unroll
      for (int i = 0; i < 4; ++i)
#pragma unroll
        for (int r = 0; r < 4; ++r) {
          float z = Zac[i][r];
          z += __shfl_xor(z, 1);
          z += __shfl_xor(z, 2);
          z += __shfl_xor(z, 4);
          z += __shfl_xor(z, 8);
          invZ[i][r] = 1.0f / z;
        }
    }
  }

  // write O: row (b, q), col = g2*48 + dt*16 + lq
#pragma unroll
  for (int hh = 0; hh < 2; ++hh)
#pragma unroll
    for (int dt = 0; dt < 3; ++dt)
#pragma unroll
      for (int qs = 0; qs < 2; ++qs)
#pragma unroll
        for (int r = 0; r < 4; ++r) {
          size_t row = tokQ + qs * 16 + lc * 4 + r;
          int col = (h0 + hh) * 48 + dt * 16 + lq;
          obuf[row * DIM + col] = f2bf(O[hh][dt][qs][r]);
        }
}

extern "C" void kernel_launch(void* const* d_in, const int* in_sizes, int n_in,
                              void* d_out, int out_size, void* d_ws, size_t ws_size,
                              hipStream_t stream) {
  const float* x      = (const float*)d_in[0];
  const float* w_qkv  = (const float*)d_in[1];
  const float* b_qkv  = (const float*)d_in[2];
  const float* w_l    = (const float*)d_in[3];
  const float* b_l    = (const float*)d_in[4];
  const float* w_w    = (const float*)d_in[5];
  const float* b_w    = (const float*)d_in[6];
  const float* w_proj = (const float*)d_in[7];
  const float* b_proj = (const float*)d_in[8];
  float* out = (float*)d_out;

  u16* qkv_buf  = (u16*)d_ws;                     // [8192][2304] bf16
  u16* attn_buf = qkv_buf + (size_t)8192 * QKV3;  // [8192][768]  bf16

  static int attr_done = 0;
  if (!attr_done) {
    (void)hipFuncSetAttribute(reinterpret_cast<const void*>(attn_kernel),
                              hipFuncAttributeMaxDynamicSharedMemorySize,
                              ATTN_SMEM);
    attr_done = 1;
  }

  // 1) QKV projection: fp32 in (bf16 staged) -> bf16 out
  gemm_mfma<float, u16><<<dim3(QKV3 / 128, 8192 / 128), 256, 0, stream>>>(
      x, w_qkv, b_qkv, qkv_buf, 8192, QKV3, DIM);
  // 2) fused talking-heads attention (all-MFMA)
  attn_kernel<<<dim3(8 * 32), dim3(512), ATTN_SMEM, stream>>>(
      qkv_buf, w_l, b_l, w_w, b_w, attn_buf);
  // 3) output projection: bf16 A, fp32 W (bf16 staged) -> fp32 out
  gemm_mfma<u16, float><<<dim3(DIM / 128, 8192 / 128), 256, 0, stream>>>(
      attn_buf, w_proj, b_proj, out, 8192, DIM, DIM);
}

// Round 3
// 360.016 us; speedup vs baseline: 15.6242x; 1.2473x over previous
//
#include <hip/hip_runtime.h>

typedef unsigned short u16;
typedef unsigned int u32;
using short8 = __attribute__((__ext_vector_type__(8))) short;
using f32x4  = __attribute__((__ext_vector_type__(4))) float;

#define DIM 768
#define QKV3 2304
#define SEQ 1024
#define SCALE 0.14433756729740643f  // 48^-0.5

// f32 -> bf16 RNE via compiler-native cast (emits the HW cvt; order-safe)
__device__ __forceinline__ u16 f2bf(float f) {
  __bf16 h = (__bf16)f;
  u16 r;
  __builtin_memcpy(&r, &h, 2);
  return r;
}
__device__ __forceinline__ u32 packbf(float lo, float hi) {
  return (u32)f2bf(lo) | ((u32)f2bf(hi) << 16);
}
__device__ __forceinline__ void store1(u16* p, float v) { *p = f2bf(v); }
__device__ __forceinline__ void store1(float* p, float v) { *p = v; }

__device__ __forceinline__ f32x4 mfma16(short8 a, short8 b, f32x4 c) {
  return __builtin_amdgcn_mfma_f32_16x16x32_bf16(a, b, c, 0, 0, 0);
}

// ---------------- fp32 -> bf16 bulk convert (8 elems/thread) ----------------
__global__ __launch_bounds__(256)
void cvt_f32_bf16(const float* __restrict__ src, u16* __restrict__ dst, int n8) {
  int i = blockIdx.x * 256 + threadIdx.x;
  if (i < n8) {
    float4 a = ((const float4*)src)[2 * i];
    float4 b = ((const float4*)src)[2 * i + 1];
    uint4 o = {packbf(a.x, a.y), packbf(a.z, a.w), packbf(b.x, b.y), packbf(b.z, b.w)};
    ((uint4*)dst)[i] = o;
  }
}

// ---------------- MFMA GEMM: C[M][N] = A[M][K] @ W[N][K]^T + bias[N]
// A bf16, W fp32 (bf16-staged). 128x128 tile, BK=32, 4 waves, reg-prefetch.
// Round-1 verified operand order and epilogue mapping.
template <typename TO>
__global__ __launch_bounds__(256, 2)
void gemm_mfma(const u16* __restrict__ A, const float* __restrict__ W,
               const float* __restrict__ bias, TO* __restrict__ C,
               int M, int N, int K) {
  __shared__ __align__(16) u16 As[128 * 40];  // [row][k pad 40] bf16
  __shared__ __align__(16) u16 Bs[128 * 40];
  const int tid = threadIdx.x;
  const int lane = tid & 63;
  const int wv = tid >> 6;
  const int lq = lane & 15;
  const int lc = lane >> 4;
  const int wm = wv >> 1, wn = wv & 1;
  const int row0 = blockIdx.y * 128, col0 = blockIdx.x * 128;

  f32x4 acc[4][4];
#pragma unroll
  for (int i = 0; i < 4; ++i)
#pragma unroll
    for (int j = 0; j < 4; ++j) acc[i][j] = (f32x4){0.f, 0.f, 0.f, 0.f};

  short8 pa[2];
  float4 pw[2][2];
  auto issue = [&](int k0) {
#pragma unroll
    for (int t = 0; t < 2; ++t) {
      int id = t * 256 + tid;
      int r = id >> 2, kc = (id & 3) * 8;
      pa[t] = *(const short8*)(A + (size_t)(row0 + r) * K + k0 + kc);
      const float* wp = W + (size_t)(col0 + r) * K + k0 + kc;
      pw[t][0] = *(const float4*)wp;
      pw[t][1] = *(const float4*)(wp + 4);
    }
  };

  issue(0);
#pragma unroll 1
  for (int k0 = 0; k0 < K; k0 += 32) {
    __syncthreads();
#pragma unroll
    for (int t = 0; t < 2; ++t) {
      int id = t * 256 + tid;
      int r = id >> 2, kc = (id & 3) * 8;
      *(short8*)(As + r * 40 + kc) = pa[t];
      uint4 wq = {packbf(pw[t][0].x, pw[t][0].y), packbf(pw[t][0].z, pw[t][0].w),
                  packbf(pw[t][1].x, pw[t][1].y), packbf(pw[t][1].z, pw[t][1].w)};
      *(uint4*)(Bs + r * 40 + kc) = wq;
    }
    if (k0 + 32 < K) issue(k0 + 32);
    __syncthreads();
    short8 af[4], bf8[4];
#pragma unroll
    for (int i = 0; i < 4; ++i)
      af[i] = *(const short8*)(As + (wm * 64 + i * 16 + lq) * 40 + lc * 8);
#pragma unroll
    for (int j = 0; j < 4; ++j)
      bf8[j] = *(const short8*)(Bs + (wn * 64 + j * 16 + lq) * 40 + lc * 8);
#pragma unroll
    for (int i = 0; i < 4; ++i)
#pragma unroll
      for (int j = 0; j < 4; ++j)
        acc[i][j] = mfma16(af[i], bf8[j], acc[i][j]);  // C[row=lc*4+r][col=lq]
  }
#pragma unroll
  for (int j = 0; j < 4; ++j) {
    int col = col0 + wn * 64 + j * 16 + lq;
    float bv = bias[col];
#pragma unroll
    for (int i = 0; i < 4; ++i)
#pragma unroll
      for (int r = 0; r < 4; ++r) {
        int row = row0 + wm * 64 + i * 16 + lc * 4 + r;
        store1(C + (size_t)row * N + col, acc[i][j][r] + bv);
      }
  }
}

// ---------------- Fused talking-heads attention, all-MFMA ----------------
// Block = (batch b, 32-query tile), 512 threads = 8 waves, KT=32 keys/tile.
// Round-1 verified layouts + async-STAGE prefetch: K/V for kt+1 are loaded
// into registers right after the LDS write of tile kt (latency hides under
// QK+mix+PV).
#define KS_ELEMS 24848
#define ATTN_SMEM 160832

__global__ __launch_bounds__(512, 2)
void attn_kernel(const u16* __restrict__ qkv,
                 const float* __restrict__ wl, const float* __restrict__ bl,
                 const float* __restrict__ ww, const float* __restrict__ bw,
                 u16* __restrict__ obuf) {
  extern __shared__ __align__(16) u16 smem[];
  u16* const Ks = smem;                 // [32 k][776] bf16 (pad-tail zeroed)
  u16* const Sb = smem + KS_ELEMS;      // [32 q][776]: S/P at k*24+h, W2 at g2*40+k
  u16* const Vs = smem + 2 * KS_ELEMS;  // [768 d][40 k-pad] transposed V

  const int tid = threadIdx.x;
  const int wv = tid >> 6;
  const int lane = tid & 63;
  const int lq = lane & 15;
  const int lc = lane >> 4;
  const int b = blockIdx.x >> 5;
  const int qt = blockIdx.x & 31;
  const size_t tokQ = (size_t)b * SEQ + (size_t)qt * 32;
  const size_t tokB = (size_t)b * SEQ;
  const int h0 = wv * 2;  // wave's head pair (QK) / g2 pair (PV)

  {  // zero Ks+Sb once (pads must be finite for A=0-masked MFMA reads)
    u32* z = (u32*)smem;
    for (int i = tid; i < KS_ELEMS; i += 512) z[i] = 0u;
  }

  // Q fragments in registers: A[row=q(lq)][kd=d(lc*8+e)], d 48..63 zero
  short8 qf[2][2][2];  // [hh][qsub][dchunk]
#pragma unroll
  for (int hh = 0; hh < 2; ++hh)
#pragma unroll
    for (int qs = 0; qs < 2; ++qs) {
      const u16* qp = qkv + (tokQ + qs * 16 + lq) * QKV3 + (h0 + hh) * 48;
      qf[hh][qs][0] = *(const short8*)(qp + lc * 8);
      short8 z8 = {0, 0, 0, 0, 0, 0, 0, 0};
      if (lc < 2) z8 = *(const short8*)(qp + 32 + lc * 8);
      qf[hh][qs][1] = z8;
    }

  // mix A-frags: wl' = wl*SCALE (scale folded), zero-padded h 16..31
  short8 wlF = {0, 0, 0, 0, 0, 0, 0, 0};
  short8 wwF = {0, 0, 0, 0, 0, 0, 0, 0};
  if (lc < 2) {
#pragma unroll
    for (int e = 0; e < 8; ++e) {
      wlF[e] = (short)f2bf(wl[lq * 16 + lc * 8 + e] * SCALE);
      wwF[e] = (short)f2bf(ww[lq * 16 + lc * 8 + e]);
    }
  }
  float blr[4], bwr[4];
#pragma unroll
  for (int r = 0; r < 4; ++r) { blr[r] = bl[lc * 4 + r]; bwr[r] = bw[lc * 4 + r]; }

  // ---- prefetch machinery (global -> regs early; LDS write after barrier)
  short8 kpre[6], vA[3], vB[3];
  auto issueK = [&](int kt) {
#pragma unroll
    for (int t = 0; t < 6; ++t) {
      int j = t * 512 + tid;
      int kr = j / 96, cc = j - kr * 96;
      kpre[t] = *(const short8*)(qkv + (tokB + (size_t)kt * 32 + kr) * QKV3 + DIM + cc * 8);
    }
  };
  auto issueV = [&](int kt) {
#pragma unroll
    for (int t = 0; t < 3; ++t) {
      int cc = (tid >> 4) + t * 32;
      int kk = tid & 15;
      const u16* v0 = qkv + (tokB + (size_t)kt * 32 + 2 * kk) * QKV3 + 2 * DIM + cc * 8;
      vA[t] = *(const short8*)v0;
      vB[t] = *(const short8*)(v0 + QKV3);
    }
  };
  auto writeK = [&]() {
#pragma unroll
    for (int t = 0; t < 6; ++t) {
      int j = t * 512 + tid;
      int kr = j / 96, cc = j - kr * 96;
      *(short8*)(Ks + kr * 776 + cc * 8) = kpre[t];
    }
  };
  auto writeV = [&]() {
#pragma unroll
    for (int t = 0; t < 3; ++t) {
      int cc = (tid >> 4) + t * 32;
      int kk = tid & 15;
#pragma unroll
      for (int e = 0; e < 8; ++e)
        *(u32*)(Vs + (cc * 8 + e) * 40 + 2 * kk) =
            (u32)(u16)vA[t][e] | ((u32)(u16)vB[t][e] << 16);
    }
  };
  auto doQK = [&]() {
#pragma unroll
    for (int ks = 0; ks < 2; ++ks) {
      short8 kf[2][2];
#pragma unroll
      for (int hh = 0; hh < 2; ++hh) {
        const u16* kb = Ks + (ks * 16 + lq) * 776 + (h0 + hh) * 48;
        kf[hh][0] = *(const short8*)(kb + lc * 8);
        kf[hh][1] = *(const short8*)(kb + 32 + lc * 8);  // tail dont-care (A=0)
      }
#pragma unroll
      for (int qs = 0; qs < 2; ++qs) {
        f32x4 s0 = {0.f, 0.f, 0.f, 0.f}, s1 = {0.f, 0.f, 0.f, 0.f};
        s0 = mfma16(qf[0][qs][0], kf[0][0], s0);
        s0 = mfma16(qf[0][qs][1], kf[0][1], s0);
        s1 = mfma16(qf[1][qs][0], kf[1][0], s1);
        s1 = mfma16(qf[1][qs][1], kf[1][1], s1);
#pragma unroll
        for (int r = 0; r < 4; ++r) {
          int q = qs * 16 + lc * 4 + r;
          int k = ks * 16 + lq;
          *(u32*)(Sb + q * 776 + k * 24 + h0) = packbf(s0[r], s1[r]);
        }
      }
    }
  };

  float Zac[4][4], invZ[4][4];
#pragma unroll
  for (int i = 0; i < 4; ++i)
#pragma unroll
    for (int r = 0; r < 4; ++r) Zac[i][r] = 0.f;

  f32x4 O[2][3][2];  // [hh][dtile][qsub]
#pragma unroll
  for (int hh = 0; hh < 2; ++hh)
#pragma unroll
    for (int dt = 0; dt < 3; ++dt)
#pragma unroll
      for (int qs = 0; qs < 2; ++qs) O[hh][dt][qs] = (f32x4){0.f, 0.f, 0.f, 0.f};

  // ================= pass 0: softmax denominators =================
  issueK(0);
#pragma unroll 1
  for (int kt = 0; kt < 32; ++kt) {
    __syncthreads();   // Ks free (prev readers done); orders zero-fill too
    writeK();
    if (kt + 1 < 32) issueK(kt + 1);
    else { issueK(0); issueV(0); }   // bridge into pass 1
    __syncthreads();   // tile ready
    doQK();
    __syncthreads();   // Sb visible cross-wave
#pragma unroll
    for (int i = 0; i < 4; ++i) {
      const int q = wv * 4 + i;
      const u16* sq = Sb + q * 776;
#pragma unroll
      for (int ks = 0; ks < 2; ++ks) {
        short8 sf = *(const short8*)(sq + (ks * 16 + lq) * 24 + lc * 8);
        f32x4 cin = {blr[0], blr[1], blr[2], blr[3]};
        f32x4 L = mfma16(wlF, sf, cin);  // L[g=lc*4+r][k=ks*16+lq]
#pragma unroll
        for (int r = 0; r < 4; ++r) Zac[i][r] += __expf(L[r]);
      }
    }
  }
  // reduce Z over the 16 k-lanes
#pragma unroll
  for (int i = 0; i < 4; ++i)
#pragma unroll
    for (int r = 0; r < 4; ++r) {
      float z = Zac[i][r];
      z += __shfl_xor(z, 1);
      z += __shfl_xor(z, 2);
      z += __shfl_xor(z, 4);
      z += __shfl_xor(z, 8);
      invZ[i][r] = 1.0f / z;
    }

  // ================= pass 1: P, W2, O =================
#pragma unroll 1
  for (int kt = 0; kt < 32; ++kt) {
    __syncthreads();
    writeK();
    writeV();
    if (kt + 1 < 32) { issueK(kt + 1); issueV(kt + 1); }
    __syncthreads();
    doQK();
    __syncthreads();
#pragma unroll
    for (int i = 0; i < 4; ++i) {
      const int q = wv * 4 + i;
      u16* const sq = Sb + q * 776;
      f32x4 L[2];
#pragma unroll
      for (int ks = 0; ks < 2; ++ks) {
        short8 sf = *(const short8*)(sq + (ks * 16 + lq) * 24 + lc * 8);
        f32x4 cin = {blr[0], blr[1], blr[2], blr[3]};
        L[ks] = mfma16(wlF, sf, cin);
      }
#pragma unroll
      for (int ks = 0; ks < 2; ++ks) {
        float p0 = __expf(L[ks][0]) * invZ[i][0];
        float p1 = __expf(L[ks][1]) * invZ[i][1];
        float p2 = __expf(L[ks][2]) * invZ[i][2];
        float p3 = __expf(L[ks][3]) * invZ[i][3];
        u16* pp = sq + (ks * 16 + lq) * 24 + lc * 4;
        *(u32*)pp = packbf(p0, p1);
        *(u32*)(pp + 2) = packbf(p2, p3);
      }
      f32x4 W2[2];
#pragma unroll
      for (int ks = 0; ks < 2; ++ks) {
        short8 pf = *(const short8*)(sq + (ks * 16 + lq) * 24 + lc * 8);
        f32x4 cin = {bwr[0], bwr[1], bwr[2], bwr[3]};
        W2[ks] = mfma16(wwF, pf, cin);  // W2[g2=lc*4+r][k]
      }
#pragma unroll
      for (int ks = 0; ks < 2; ++ks)
#pragma unroll
        for (int r = 0; r < 4; ++r)
          sq[(lc * 4 + r) * 40 + ks * 16 + lq] = f2bf(W2[ks][r]);
    }
    __syncthreads();  // W2 visible to all waves
    // ---- PV: wave's g2 pair; O[q][d] += W2[g2][q][k] * V[k][g2*48+d]
#pragma unroll
    for (int hh = 0; hh < 2; ++hh) {
      const int g2 = h0 + hh;
      short8 w2f[2];
#pragma unroll
      for (int qs = 0; qs < 2; ++qs)
        w2f[qs] = *(const short8*)(Sb + (qs * 16 + lq) * 776 + g2 * 40 + lc * 8);
#pragma unroll
      for (int dt = 0; dt < 3; ++dt) {
        short8 vf = *(const short8*)(Vs + (g2 * 48 + dt * 16 + lq) * 40 + lc * 8);
#pragma unroll
        for (int qs = 0; qs < 2; ++qs)
          O[hh][dt][qs] = mfma16(w2f[qs], vf, O[hh][dt][qs]);  // C[q=lc*4+r][d=lq]
      }
    }
  }

  // write O: row (b,q), col = g2*48 + dt*16 + lq  (round-1 verified mapping)
#pragma unroll
  for (int hh = 0; hh < 2; ++hh)
#pragma unroll
    for (int dt = 0; dt < 3; ++dt)
#pragma unroll
      for (int qs = 0; qs < 2; ++qs)
#pragma unroll
        for (int r = 0; r < 4; ++r) {
          size_t row = tokQ + qs * 16 + lc * 4 + r;
          int col = (h0 + hh) * 48 + dt * 16 + lq;
          obuf[row * DIM + col] = f2bf(O[hh][dt][qs][r]);
        }
}

extern "C" void kernel_launch(void* const* d_in, const int* in_sizes, int n_in,
                              void* d_out, int out_size, void* d_ws, size_t ws_size,
                              hipStream_t stream) {
  const float* x      = (const float*)d_in[0];
  const float* w_qkv  = (const float*)d_in[1];
  const float* b_qkv  = (const float*)d_in[2];
  const float* w_l    = (const float*)d_in[3];
  const float* b_l    = (const float*)d_in[4];
  const float* w_w    = (const float*)d_in[5];
  const float* b_w    = (const float*)d_in[6];
  const float* w_proj = (const float*)d_in[7];
  const float* b_proj = (const float*)d_in[8];
  float* out = (float*)d_out;

  u16* qkv_buf  = (u16*)d_ws;                     // [8192][2304] bf16
  u16* attn_buf = qkv_buf + (size_t)8192 * QKV3;  // [8192][768]  bf16
  u16* x_bf     = attn_buf;  // alias: region is free until attn_kernel writes it

  static int attr_done = 0;
  if (!attr_done) {
    (void)hipFuncSetAttribute(reinterpret_cast<const void*>(attn_kernel),
                              hipFuncAttributeMaxDynamicSharedMemorySize,
                              ATTN_SMEM);
    attr_done = 1;
  }

  // 0) x fp32 -> bf16 (8192*768 / 8 = 786432 vec8 chunks)
  cvt_f32_bf16<<<dim3(786432 / 256), 256, 0, stream>>>(x, x_bf, 786432);
  // 1) QKV projection: bf16 A, fp32 W (bf16-staged) -> bf16 out
  gemm_mfma<u16><<<dim3(QKV3 / 128, 8192 / 128), 256, 0, stream>>>(
      x_bf, w_qkv, b_qkv, qkv_buf, 8192, QKV3, DIM);
  // 2) fused talking-heads attention (all-MFMA, async-staged)
  attn_kernel<<<dim3(8 * 32), dim3(512), ATTN_SMEM, stream>>>(
      qkv_buf, w_l, b_l, w_w, b_w, attn_buf);
  // 3) output projection: bf16 A, fp32 W -> fp32 out
  gemm_mfma<float><<<dim3(DIM / 128, 8192 / 128), 256, 0, stream>>>(
      attn_buf, w_proj, b_proj, out, 8192, DIM, DIM);
}